// Round 2
// 24507.669 us; speedup vs baseline: 1.0360x; 1.0360x over previous
//
#include <hip/hip_runtime.h>
#include <cstdint>

#define NN   50000
#define TT   128
#define EE   1600000
#define CIN  16
#define CH   32
#define COUT 8

// ---------- helpers ----------
__device__ __forceinline__ float rlane(float v, int k) {
  return __int_as_float(__builtin_amdgcn_readlane(__float_as_int(v), k));
}
__device__ __forceinline__ float xhalf(float v) {  // add value from other 32-lane half
  return __shfl_xor(v, 32, 64);
}
__device__ __forceinline__ float sigf(float x) {
  return 1.0f / (1.0f + __expf(-x));
}
__device__ __forceinline__ float tanh_fast(float x) {
  x = fminf(fmaxf(x, -30.0f), 30.0f);
  float e = __expf(2.0f * x);
  return (e - 1.0f) / (e + 1.0f);
}

// ---------- setup kernels (verified) ----------
__global__ void k_flag(const int* __restrict__ idx, int* __restrict__ flag) {
  if (threadIdx.x == 0) {
    int m = 1;
    for (int i = 1; i <= 32; ++i)
      if (idx[2 * i + 1] != 0) m = 0;
    flag[0] = m;
  }
}

__global__ void k_zero_i(int* __restrict__ p, int n) {
  int i = blockIdx.x * blockDim.x + threadIdx.x;
  if (i < n) p[i] = 0;
}
__global__ void k_zero_f(float* __restrict__ p, int n) {
  int i = blockIdx.x * blockDim.x + threadIdx.x;
  if (i < n) p[i] = 0.0f;
}

__global__ void k_deg(const int* __restrict__ idx, int* __restrict__ deg_s,
                      int* __restrict__ deg_d, const int* __restrict__ flag) {
  int e = blockIdx.x * blockDim.x + threadIdx.x;
  if (e >= EE) return;
  int m = flag[0];
  int s = m ? idx[2 * e] : idx[e];
  int d = m ? idx[2 * (EE + e)] : idx[EE + e];
  atomicAdd(&deg_s[s], 1);
  atomicAdd(&deg_d[d], 1);
}

__global__ void k_dinv(const int* __restrict__ deg_s, float* __restrict__ dinv) {
  int i = blockIdx.x * blockDim.x + threadIdx.x;
  if (i < NN) {
    int d = deg_s[i];
    dinv[i] = (d > 0) ? rsqrtf((float)d) : 0.0f;
  }
}

__global__ void k_scan(const int* __restrict__ deg, int* __restrict__ row_ptr,
                       int* __restrict__ cursor) {
  __shared__ int part[1024];
  int tid = threadIdx.x;
  const int chunk = (NN + 1023) / 1024;
  int b = tid * chunk;
  int e = b + chunk; if (e > NN) e = NN;
  int s = 0;
  for (int j = b; j < e; ++j) s += deg[j];
  part[tid] = s;
  __syncthreads();
  for (int off = 1; off < 1024; off <<= 1) {
    int v = part[tid];
    int add = (tid >= off) ? part[tid - off] : 0;
    __syncthreads();
    part[tid] = v + add;
    __syncthreads();
  }
  int run = (tid > 0) ? part[tid - 1] : 0;
  for (int j = b; j < e; ++j) {
    row_ptr[j] = run; cursor[j] = run;
    run += deg[j];
  }
  if (tid == 1023) row_ptr[NN] = part[1023];
}

// fused (col, weight) per edge: .x = src node, .y = bits of weight
__global__ void k_fill(const int* __restrict__ idx, const float* __restrict__ dinv,
                       int* __restrict__ cursor, int2* __restrict__ cw,
                       const int* __restrict__ flag) {
  int e = blockIdx.x * blockDim.x + threadIdx.x;
  if (e >= EE) return;
  int m = flag[0];
  int s = m ? idx[2 * e] : idx[e];
  int d = m ? idx[2 * (EE + e)] : idx[EE + e];
  int p = atomicAdd(&cursor[d], 1);
  int2 v;
  v.x = s;
  v.y = __float_as_int(-dinv[s] * dinv[d]);
  cw[p] = v;
}

// ---------- x-side ----------
// kx_all: batched over ALL timesteps (t-quads). wave = 1 node, 4 consecutive t.
// Writes Gx[t][n][96] = x-contributions for z | r | candidate (biases folded).
__global__ __launch_bounds__(256, 3) void kx_all(
    const float* __restrict__ X,
    const int* __restrict__ row_ptr, const int2* __restrict__ cw,
    const float* __restrict__ W_xz, const float* __restrict__ b_xz,
    const float* __restrict__ b_hz,
    const float* __restrict__ W_xr, const float* __restrict__ b_xr,
    const float* __restrict__ b_hr,
    const float* __restrict__ W_xh, const float* __restrict__ b_xh,
    const float* __restrict__ b_hh,
    float* __restrict__ Gx) {
  const int lane = threadIdx.x & 63;
  const int g = lane >> 5;
  const int c = lane & 31;
  const int ci = c & 15;
  const int tq = blockIdx.x / 12500;            // t-quad (32 of them)
  const int t0 = tq * 4;
  const int node = (blockIdx.x % 12500) * 4 + (threadIdx.x >> 6);
  const int iu = __builtin_amdgcn_readfirstlane(node);

  const float* Wzr = g ? W_xr : W_xz;           // [2][16][32]
  float w0[CIN], w1[CIN], wh0[CIN], wh1[CIN];
#pragma unroll
  for (int k = 0; k < CIN; ++k) {
    w0[k]  = Wzr[k * CH + c];
    w1[k]  = Wzr[CIN * CH + k * CH + c];
    wh0[k] = W_xh[k * CH + c];
    wh1[k] = W_xh[CIN * CH + k * CH + c];
  }
  const float bzr = g ? (b_xr[c] + b_hr[c]) : (b_xz[c] + b_hz[c]);
  const float bh  = b_xh[c] + b_hh[c];

  const int e0 = __builtin_amdgcn_readfirstlane(row_ptr[iu]);
  const int e1 = __builtin_amdgcn_readfirstlane(row_ptr[iu + 1]);
  const int deg = e1 - e0;
  const int len0 = (deg + 1) >> 1;
  const int s = e0 + (g ? len0 : 0);
  const int send = g ? e1 : (e0 + len0);

  float ax4[4] = {0.f, 0.f, 0.f, 0.f};
  int j = s;
  for (; j + 4 <= send; j += 4) {
    const int2 q0 = cw[j], q1 = cw[j + 1], q2 = cw[j + 2], q3 = cw[j + 3];
    const int c0 = q0.x, c1 = q1.x, c2 = q2.x, c3 = q3.x;
    const float wA = __int_as_float(q0.y), wB = __int_as_float(q1.y);
    const float wC = __int_as_float(q2.y), wD = __int_as_float(q3.y);
#pragma unroll
    for (int tp = 0; tp < 4; ++tp) {
      const float* Xt = X + (size_t)(t0 + tp) * NN * CIN;
      ax4[tp] += wA * Xt[c0 * CIN + ci] + wB * Xt[c1 * CIN + ci]
               + wC * Xt[c2 * CIN + ci] + wD * Xt[c3 * CIN + ci];
    }
  }
  for (; j < send; ++j) {
    const int2 q = cw[j];
    const int cs = q.x;
    const float wv = __int_as_float(q.y);
#pragma unroll
    for (int tp = 0; tp < 4; ++tp)
      ax4[tp] += wv * (X + (size_t)(t0 + tp) * NN * CIN)[cs * CIN + ci];
  }
#pragma unroll
  for (int tp = 0; tp < 4; ++tp)
    ax4[tp] += xhalf(ax4[tp]);    // full agg(x_t)[ci]

#pragma unroll
  for (int tp = 0; tp < 4; ++tp) {
    const float* xrow = X + ((size_t)(t0 + tp) * NN + iu) * CIN;
    float accA = bzr, accH = bh;
#pragma unroll
    for (int k = 0; k < CIN; ++k) {
      float xk = xrow[k];
      float axk = rlane(ax4[tp], k);
      accA += xk * w0[k] + axk * w1[k];
      accH += xk * wh0[k] + axk * wh1[k];
    }
    float* grow = Gx + ((size_t)(t0 + tp) * NN + iu) * 96;
    grow[g * CH + c] = accA;
    if (g == 0) grow[64 + c] = accH;
  }
}

// kx: per-step fallback when ws too small for Gx-all.
__global__ __launch_bounds__(256, 4) void kx(
    const float* __restrict__ Xt,
    const int* __restrict__ row_ptr, const int2* __restrict__ cw,
    const float* __restrict__ W_xz, const float* __restrict__ b_xz,
    const float* __restrict__ b_hz,
    const float* __restrict__ W_xr, const float* __restrict__ b_xr,
    const float* __restrict__ b_hr,
    const float* __restrict__ W_xh, const float* __restrict__ b_xh,
    const float* __restrict__ b_hh,
    float* __restrict__ Gx) {
  const int lane = threadIdx.x & 63;
  const int g = lane >> 5;
  const int c = lane & 31;
  const int ci = c & 15;
  const int wid = (blockIdx.x * blockDim.x + threadIdx.x) >> 6;
  const int nw = (gridDim.x * blockDim.x) >> 6;

  const float* Wzr = g ? W_xr : W_xz;
  float w0[CIN], w1[CIN], wh0[CIN], wh1[CIN];
#pragma unroll
  for (int k = 0; k < CIN; ++k) {
    w0[k]  = Wzr[k * CH + c];
    w1[k]  = Wzr[CIN * CH + k * CH + c];
    wh0[k] = W_xh[k * CH + c];
    wh1[k] = W_xh[CIN * CH + k * CH + c];
  }
  const float bzr = g ? (b_xr[c] + b_hr[c]) : (b_xz[c] + b_hz[c]);
  const float bh  = b_xh[c] + b_hh[c];

  for (int i = wid; i < NN; i += nw) {
    const int iu = __builtin_amdgcn_readfirstlane(i);
    const int e0 = __builtin_amdgcn_readfirstlane(row_ptr[iu]);
    const int e1 = __builtin_amdgcn_readfirstlane(row_ptr[iu + 1]);
    const int deg = e1 - e0;
    const int len0 = (deg + 1) >> 1;
    const int s = e0 + (g ? len0 : 0);
    const int send = g ? e1 : (e0 + len0);
    float a[4] = {0.f, 0.f, 0.f, 0.f};
    int j = s;
    while (j < send) {
      int cidx[16]; float wv[16];
#pragma unroll
      for (int k = 0; k < 16; ++k) {
        int jk = j + k;
        int sj = (jk < send) ? jk : (send - 1);
        const int2 q = cw[sj];
        cidx[k] = q.x;
        wv[k] = (jk < send) ? __int_as_float(q.y) : 0.0f;
      }
#pragma unroll
      for (int k = 0; k < 16; ++k)
        a[k & 3] += wv[k] * Xt[(size_t)cidx[k] * CIN + ci];
      j += 16;
    }
    float axh = (a[0] + a[1]) + (a[2] + a[3]);
    float ax = axh + xhalf(axh);

    const float* xrow = Xt + (size_t)iu * CIN;
    float accA = bzr, accH = bh;
#pragma unroll
    for (int k = 0; k < CIN; ++k) {
      float xk = xrow[k];
      float axk = rlane(ax, k);
      accA += xk * w0[k] + axk * w1[k];
      accH += xk * wh0[k] + axk * wh1[k];
    }
    float* grow = Gx + (size_t)iu * 96;
    grow[g * CH + c] = accA;
    if (g == 0) grow[64 + c] = accH;
  }
}

// ---------- recurrent kernels (restructured gather) ----------
// Gather layout per wave: 8 edge-slots (grp = lane>>3) x 8 channel-quads
// (qb = (lane&7)*4). One float4 load per lane covers 8 neighbor rows / instr
// (1 KB). Two slots in flight per loop iter (16 edges). Butterfly shfl_xor
// over the grp axis leaves the FULL aggregate replicated in every lane;
// the dense matmul then broadcasts it via readlane (layout: channel k lives
// in component k&3 of lane k>>2).

// k1: agg(h) -> Z gate, h*R. Gxt = x-contribution slab for this t.
__global__ __launch_bounds__(256, 4) void k1(
    const float* __restrict__ h,
    const int* __restrict__ row_ptr, const int2* __restrict__ cw,
    const float* __restrict__ W_hz, const float* __restrict__ W_hr,
    const float* __restrict__ Gxt,
    float* __restrict__ Zb, float* __restrict__ hrb) {
  const int lane = threadIdx.x & 63;
  const int g = lane >> 5;
  const int c = lane & 31;
  const int grp = lane >> 3;        // edge slot 0..7
  const int qb = (lane & 7) * 4;    // channel quad base
  const int wid = (blockIdx.x * blockDim.x + threadIdx.x) >> 6;
  const int nw = (gridDim.x * blockDim.x) >> 6;

  const float* Wh = g ? W_hr : W_hz;  // [2][32][32]
  float w0[CH], w1[CH];
#pragma unroll
  for (int k = 0; k < CH; ++k) {
    w0[k] = Wh[k * CH + c];
    w1[k] = Wh[CH * CH + k * CH + c];
  }

  for (int i = wid; i < NN; i += nw) {
    const int iu = __builtin_amdgcn_readfirstlane(i);
    const int e0 = __builtin_amdgcn_readfirstlane(row_ptr[iu]);
    const int e1 = __builtin_amdgcn_readfirstlane(row_ptr[iu + 1]);

    float ax = 0.f, ay = 0.f, az = 0.f, aw = 0.f;
    float bx = 0.f, by = 0.f, bz = 0.f, bw = 0.f;
    for (int j = e0; j < e1; j += 16) {
      const int j0 = j + grp, j1 = j + 8 + grp;
      const bool v0 = j0 < e1, v1 = j1 < e1;
      const int s0 = v0 ? j0 : e0, s1 = v1 ? j1 : e0;
      const int2 q0 = cw[s0], q1 = cw[s1];
      const float we0 = v0 ? __int_as_float(q0.y) : 0.0f;
      const float we1 = v1 ? __int_as_float(q1.y) : 0.0f;
      const float4 h0 = *(const float4*)(h + (size_t)q0.x * CH + qb);
      const float4 h1 = *(const float4*)(h + (size_t)q1.x * CH + qb);
      ax += we0 * h0.x; ay += we0 * h0.y; az += we0 * h0.z; aw += we0 * h0.w;
      bx += we1 * h1.x; by += we1 * h1.y; bz += we1 * h1.z; bw += we1 * h1.w;
    }
    ax += bx; ay += by; az += bz; aw += bw;
#pragma unroll
    for (int off = 8; off < 64; off <<= 1) {
      ax += __shfl_xor(ax, off, 64);
      ay += __shfl_xor(ay, off, 64);
      az += __shfl_xor(az, off, 64);
      aw += __shfl_xor(aw, off, 64);
    }
    float ag[4] = {ax, ay, az, aw};

    const float* __restrict__ hrow = h + (size_t)iu * CH;
    float acA = __builtin_nontemporal_load(Gxt + (size_t)iu * 96 + g * CH + c);
    float acB = 0.0f;
#pragma unroll
    for (int k = 0; k < CH; k += 2) {
      acA += hrow[k]     * w0[k]     + rlane(ag[k & 3], k >> 2)             * w1[k];
      acB += hrow[k + 1] * w0[k + 1] + rlane(ag[(k + 1) & 3], (k + 1) >> 2) * w1[k + 1];
    }
    float sg = sigf(acA + acB);
    if (g == 0) Zb[(size_t)iu * CH + c] = sg;
    else        hrb[(size_t)iu * CH + c] = hrow[c] * sg;
  }
}

// k2: agg(h*R) -> candidate, h update, fused FC output.
__global__ __launch_bounds__(256, 3) void k2(
    float* __restrict__ h, const float* __restrict__ hrb,
    const int* __restrict__ row_ptr, const int2* __restrict__ cw,
    const float* __restrict__ W_hh,
    const float* __restrict__ fc_w, const float* __restrict__ fc_b,
    const float* __restrict__ Gxt, const float* __restrict__ Zb,
    float* __restrict__ outT) {
  const int lane = threadIdx.x & 63;
  const int g = lane >> 5;
  const int c = lane & 31;
  const int grp = lane >> 3;
  const int qb = (lane & 7) * 4;
  const int wid = (blockIdx.x * blockDim.x + threadIdx.x) >> 6;
  const int nw = (gridDim.x * blockDim.x) >> 6;

  float w0[CH], w1[CH], fcw[CH];
#pragma unroll
  for (int k = 0; k < CH; ++k) {
    w0[k] = W_hh[k * CH + c];
    w1[k] = W_hh[CH * CH + k * CH + c];
    fcw[k] = fc_w[k * COUT + (c & 7)];
  }
  const float fb = fc_b[c & 7];

  for (int i = wid; i < NN; i += nw) {
    const int iu = __builtin_amdgcn_readfirstlane(i);
    const int e0 = __builtin_amdgcn_readfirstlane(row_ptr[iu]);
    const int e1 = __builtin_amdgcn_readfirstlane(row_ptr[iu + 1]);

    float ax = 0.f, ay = 0.f, az = 0.f, aw = 0.f;
    float bx = 0.f, by = 0.f, bz = 0.f, bw = 0.f;
    for (int j = e0; j < e1; j += 16) {
      const int j0 = j + grp, j1 = j + 8 + grp;
      const bool v0 = j0 < e1, v1 = j1 < e1;
      const int s0 = v0 ? j0 : e0, s1 = v1 ? j1 : e0;
      const int2 q0 = cw[s0], q1 = cw[s1];
      const float we0 = v0 ? __int_as_float(q0.y) : 0.0f;
      const float we1 = v1 ? __int_as_float(q1.y) : 0.0f;
      const float4 h0 = *(const float4*)(hrb + (size_t)q0.x * CH + qb);
      const float4 h1 = *(const float4*)(hrb + (size_t)q1.x * CH + qb);
      ax += we0 * h0.x; ay += we0 * h0.y; az += we0 * h0.z; aw += we0 * h0.w;
      bx += we1 * h1.x; by += we1 * h1.y; bz += we1 * h1.z; bw += we1 * h1.w;
    }
    ax += bx; ay += by; az += bz; aw += bw;
#pragma unroll
    for (int off = 8; off < 64; off <<= 1) {
      ax += __shfl_xor(ax, off, 64);
      ay += __shfl_xor(ay, off, 64);
      az += __shfl_xor(az, off, 64);
      aw += __shfl_xor(aw, off, 64);
    }
    float ag[4] = {ax, ay, az, aw};

    const float* __restrict__ hrrow = hrb + (size_t)iu * CH;
    float acA = __builtin_nontemporal_load(Gxt + (size_t)iu * 96 + 64 + c);
    float acB = 0.0f;
#pragma unroll
    for (int k = 0; k < CH; k += 2) {
      acA += hrrow[k]     * w0[k]     + rlane(ag[k & 3], k >> 2)             * w1[k];
      acB += hrrow[k + 1] * w0[k + 1] + rlane(ag[(k + 1) & 3], (k + 1) >> 2) * w1[k + 1];
    }
    float ht = tanh_fast(acA + acB);
    float zv = Zb[(size_t)iu * CH + c];
    float hv = h[(size_t)iu * CH + c];
    float hn = zv * hv + (1.0f - zv) * ht;   // identical in both halves
    if (g == 0) h[(size_t)iu * CH + c] = hn;

    float o0 = fb, o1 = 0.f;
#pragma unroll
    for (int k = 0; k < CH; k += 2) {
      o0 += rlane(hn, k) * fcw[k];
      o1 += rlane(hn, k + 1) * fcw[k + 1];
    }
    float o = o0 + o1;
    if (lane < COUT)
      __builtin_nontemporal_store(o, outT + (size_t)iu * COUT + lane);
  }
}

// ---------- host ----------
extern "C" void kernel_launch(void* const* d_in, const int* in_sizes, int n_in,
                              void* d_out, int out_size, void* d_ws, size_t ws_size,
                              hipStream_t stream) {
  const float* X = (const float*)d_in[0];
  const int* idx = (const int*)d_in[1];
  const float* W_xz = (const float*)d_in[2];  const float* b_xz = (const float*)d_in[3];
  const float* W_hz = (const float*)d_in[4];  const float* b_hz = (const float*)d_in[5];
  const float* W_xr = (const float*)d_in[6];  const float* b_xr = (const float*)d_in[7];
  const float* W_hr = (const float*)d_in[8];  const float* b_hr = (const float*)d_in[9];
  const float* W_xh = (const float*)d_in[10]; const float* b_xh = (const float*)d_in[11];
  const float* W_hh = (const float*)d_in[12]; const float* b_hh = (const float*)d_in[13];
  const float* fc_w = (const float*)d_in[14]; const float* fc_b = (const float*)d_in[15];
  float* out = (float*)d_out;

  char* ws = (char*)d_ws;
  size_t off = 0;
  auto alloc = [&](size_t bytes) -> void* {
    void* p = ws + off;
    off = (off + bytes + 255) & ~(size_t)255;
    return p;
  };
  int* flag = (int*)alloc(4);
  int* deg_s = (int*)alloc((size_t)NN * 4);
  int* deg_d = (int*)alloc((size_t)NN * 4);
  int* row_ptr = (int*)alloc((size_t)(NN + 1) * 4);
  int* cursor = (int*)alloc((size_t)NN * 4);
  float* dinv = (float*)alloc((size_t)NN * 4);
  int2* cw = (int2*)alloc((size_t)EE * 8);     // fused (col, weight)
  float* h = (float*)alloc((size_t)NN * CH * 4);
  float* hrb = (float*)alloc((size_t)NN * CH * 4);
  float* Zb = (float*)alloc((size_t)NN * CH * 4);

  const size_t gx_step = (size_t)NN * 96;              // floats per t-slab
  const size_t gxall_bytes = (size_t)TT * gx_step * 4; // ~2.46 GB
  const bool full = (ws_size >= off + gxall_bytes + (1 << 20));
  float* Gx = (float*)alloc(full ? gxall_bytes : gx_step * 4);

  k_flag<<<1, 64, 0, stream>>>(idx, flag);
  k_zero_i<<<(NN + 255) / 256, 256, 0, stream>>>(deg_s, NN);
  k_zero_i<<<(NN + 255) / 256, 256, 0, stream>>>(deg_d, NN);
  k_deg<<<(EE + 255) / 256, 256, 0, stream>>>(idx, deg_s, deg_d, flag);
  k_dinv<<<(NN + 255) / 256, 256, 0, stream>>>(deg_s, dinv);
  k_scan<<<1, 1024, 0, stream>>>(deg_d, row_ptr, cursor);
  k_fill<<<(EE + 255) / 256, 256, 0, stream>>>(idx, dinv, cursor, cw, flag);
  k_zero_f<<<(NN * CH + 255) / 256, 256, 0, stream>>>(h, NN * CH);

  if (full) {
    // one batched x-side pass over all (t-quad, node)
    kx_all<<<32 * 12500, 256, 0, stream>>>(X, row_ptr, cw,
                                           W_xz, b_xz, b_hz, W_xr, b_xr, b_hr,
                                           W_xh, b_xh, b_hh, Gx);
  }

  const int rblocks = 2048;  // 8192 waves grid-stride, ~6 nodes/wave
  for (int t = 0; t < TT; ++t) {
    float* outT = out + (size_t)t * NN * COUT;
    const float* Gxt;
    if (full) {
      Gxt = Gx + (size_t)t * gx_step;
    } else {
      const float* Xt = X + (size_t)t * NN * CIN;
      kx<<<3125, 256, 0, stream>>>(Xt, row_ptr, cw,
                                   W_xz, b_xz, b_hz, W_xr, b_xr, b_hr,
                                   W_xh, b_xh, b_hh, Gx);
      Gxt = Gx;
    }
    k1<<<rblocks, 256, 0, stream>>>(h, row_ptr, cw, W_hz, W_hr, Gxt, Zb, hrb);
    k2<<<rblocks, 256, 0, stream>>>(h, hrb, row_ptr, cw, W_hh,
                                    fc_w, fc_b, Gxt, Zb, outT);
  }
}